// Round 9
// baseline (211.939 us; speedup 1.0000x reference)
//
#include <hip/hip_runtime.h>
#include <hip/hip_fp16.h>

#define FDIM 128
#define HEADS 4
#define CD 32
#define BM 64
#define XPAD 68

static __device__ __forceinline__ unsigned short f2bf(float v) {
    unsigned u = __float_as_uint(v);
    u += 0x7FFF + ((u >> 16) & 1);          // round-nearest-even
    return (unsigned short)(u >> 16);
}
static __device__ __forceinline__ float bf2f(unsigned short u) {
    return __uint_as_float(((unsigned)u) << 16);
}

// K1: fused GEMM + logits (+ accumulator zeroing in prologue).
__global__ __launch_bounds__(256) void k_gemm(const float* __restrict__ x,
                                              const float* __restrict__ w,
                                              const float* __restrict__ att,
                                              unsigned short* __restrict__ xwh,
                                              float* __restrict__ a_src,
                                              float* __restrict__ a_dst,
                                              float4* __restrict__ zero_base,
                                              int nz4, int N)
{
    __shared__ float xs[FDIM * XPAD];    // staging [k][row]; later acc [row][132]
    __shared__ float attl[HEADS * 2 * CD];
    int t = threadIdx.x;
    int row0 = blockIdx.x * BM;
    for (int i = blockIdx.x * 256 + t; i < nz4; i += gridDim.x * 256)
        zero_base[i] = make_float4(0.f, 0.f, 0.f, 0.f);
    attl[t] = att[t];
#pragma unroll
    for (int it = 0; it < 8; it++) {
        int i = t + 256 * it;
        int row = i & 63, kq = i >> 6;
        float4 v = make_float4(0.f, 0.f, 0.f, 0.f);
        if (row0 + row < N) v = ((const float4*)x)[(size_t)(row0 + row) * 32 + kq];
        xs[(kq * 4 + 0) * XPAD + row] = v.x;
        xs[(kq * 4 + 1) * XPAD + row] = v.y;
        xs[(kq * 4 + 2) * XPAD + row] = v.z;
        xs[(kq * 4 + 3) * XPAD + row] = v.w;
    }
    __syncthreads();
    int tx = t & 31, ty = t >> 5;
    int c0 = tx * 4, r0 = ty * 8;
    const float4* w4 = (const float4*)w;
    float acc[8][4];
#pragma unroll
    for (int i = 0; i < 8; i++)
#pragma unroll
        for (int j = 0; j < 4; j++) acc[i][j] = 0.f;
#pragma unroll 4
    for (int k = 0; k < FDIM; k++) {
        float4 wv = w4[k * 32 + tx];
        float4 xa = *(const float4*)&xs[k * XPAD + r0];
        float4 xb = *(const float4*)&xs[k * XPAD + r0 + 4];
        float xr[8] = {xa.x, xa.y, xa.z, xa.w, xb.x, xb.y, xb.z, xb.w};
        float wr[4] = {wv.x, wv.y, wv.z, wv.w};
#pragma unroll
        for (int i = 0; i < 8; i++)
#pragma unroll
            for (int j = 0; j < 4; j++) acc[i][j] += xr[i] * wr[j];
    }
    int h0 = c0 >> 5, chb = c0 & 31;
#pragma unroll
    for (int i = 0; i < 8; i++) {
        int r = row0 + r0 + i;
        if (r < N) {
#pragma unroll
            for (int j = 0; j < 4; j++)
                xwh[(size_t)r * FDIM + (chb + j) * 4 + h0] = f2bf(acc[i][j]);
        }
    }
    __syncthreads();
    float* accs = xs;    // acc round-trip [row][132]
#pragma unroll
    for (int i = 0; i < 8; i++)
        *(float4*)&accs[(r0 + i) * 132 + c0] =
            make_float4(acc[i][0], acc[i][1], acc[i][2], acc[i][3]);
    __syncthreads();
    int row = t >> 2, h = t & 3;
    const float* ap = &attl[h * 2 * CD];
    const float* xr = &accs[row * 132 + h * CD];
    float s = 0.f, d = 0.f;
#pragma unroll 8
    for (int c = 0; c < CD; c++) { float v = xr[c]; s += v * ap[c]; d += v * ap[CD + c]; }
    int n = row0 + row;
    if (n < N) { a_src[n * 4 + h] = s; a_dst[n * 4 + h] = d; }
}

// K4: seg (fp16) += exp(leaky(...)) via packed-f16 atomics: lanes h=0,2 issue
// one pk_add carrying (ex_h, ex_{h+1}) -> 2 atomic dwords/edge, 8 B footprint.
__global__ __launch_bounds__(256) void k_esum(const int* __restrict__ ei, int E,
                                              const float* __restrict__ a_src,
                                              const float* __restrict__ a_dst,
                                              __half2* __restrict__ seg2,
                                              __half* __restrict__ ealpha)
{
    int gid = blockIdx.x * 256 + threadIdx.x;
    if (gid >= E * HEADS) return;
    int e = gid >> 2, h = gid & 3;
    int r = ei[e], cl = ei[E + e];
    float a = a_src[r * 4 + h] + a_dst[cl * 4 + h];
    a = a >= 0.f ? a : 0.2f * a;
    float ex = __expf(a);
    ealpha[gid] = __float2half(ex);
    float exn = __shfl_down(ex, 1, 64);     // neighbor lane's (h+1) value
    if ((h & 1) == 0)
        unsafeAtomicAdd(&seg2[(size_t)r * 2 + (h >> 1)], __floats2half2_rn(ex, exn));
}

// K5: out_acc2 += packed fp16 pair — 16 lanes/edge, 64 B atomic footprint.
// Launched twice over half the edge list (e0 offset) for profiler visibility.
__global__ __launch_bounds__(256) void k_scatter(const int* __restrict__ ei, int E,
                                                 int e0, int e1,
                                                 const __half* __restrict__ ealpha,
                                                 const __half* __restrict__ seg,
                                                 const unsigned short* __restrict__ xwh,
                                                 __half2* __restrict__ out_acc2)
{
    int t = threadIdx.x;
    int le = t >> 4, c2 = t & 15;
    int e = e0 + blockIdx.x * 16 + le;
    if (e >= e1) return;
    int r = ei[e], cl = ei[E + e];
    int lane = t & 63;
    float av = 0.f;
    if (c2 < 4)
        av = 0.25f * __half2float(ealpha[e * 4 + c2]) /
             (__half2float(seg[r * 4 + c2]) + 1e-16f);
    uint4 q = ((const uint4*)(xwh + (size_t)r * FDIM))[c2];
    float a0 = __shfl(av, (lane & 48) + 0, 64);
    float a1 = __shfl(av, (lane & 48) + 1, 64);
    float a2 = __shfl(av, (lane & 48) + 2, 64);
    float a3 = __shfl(av, (lane & 48) + 3, 64);
    float v0 = a0 * bf2f((unsigned short)(q.x & 0xFFFF)) + a1 * bf2f((unsigned short)(q.x >> 16))
             + a2 * bf2f((unsigned short)(q.y & 0xFFFF)) + a3 * bf2f((unsigned short)(q.y >> 16));
    float v1 = a0 * bf2f((unsigned short)(q.z & 0xFFFF)) + a1 * bf2f((unsigned short)(q.z >> 16))
             + a2 * bf2f((unsigned short)(q.w & 0xFFFF)) + a3 * bf2f((unsigned short)(q.w >> 16));
    unsafeAtomicAdd(&out_acc2[(size_t)cl * 16 + c2], __floats2half2_rn(v0, v1));
}

// K6: out = fp16 out_acc2 + bias
__global__ void k_final(const __half2* __restrict__ out_acc2, const float4* __restrict__ bias,
                        float4* __restrict__ out, int N)
{
    int i = blockIdx.x * 256 + threadIdx.x;
    if (i >= N * 8) return;
    float4 b = bias[i & 7];
    float2 f0 = __half22float2(out_acc2[i * 2]);
    float2 f1 = __half22float2(out_acc2[i * 2 + 1]);
    out[i] = make_float4(f0.x + b.x, f0.y + b.y, f1.x + b.z, f1.y + b.w);
}

extern "C" void kernel_launch(void* const* d_in, const int* in_sizes, int n_in,
                              void* d_out, int out_size, void* d_ws, size_t ws_size,
                              hipStream_t stream)
{
    const float* x    = (const float*)d_in[0];
    const int*   ei   = (const int*)d_in[1];
    const float* w    = (const float*)d_in[2];
    const float* att  = (const float*)d_in[3];
    const float* bias = (const float*)d_in[4];
    float* out = (float*)d_out;
    int N = in_sizes[0] / FDIM;
    int E = in_sizes[1] / 2;

    unsigned short* xwh = (unsigned short*)d_ws;              // N*128 bf16  (12.8 MB)
    float* fws      = (float*)(xwh + (size_t)N * FDIM);
    float* a_src    = fws;                                    // N*4 f32
    float* a_dst    = a_src + (size_t)N * HEADS;              // N*4 f32
    __half* seg     = (__half*)(a_dst + (size_t)N * HEADS);   // N*4 fp16  (zeroed)
    __half2* out_acc2 = (__half2*)(seg + (size_t)N * HEADS);  // N*16 half2 (zeroed, contig)
    __half* ealpha  = (__half*)(out_acc2 + (size_t)N * 16);   // E*4 fp16

    // zero region: seg (N*8 B) + out_acc2 (N*64 B) = N*72 B = N*4.5 float4 (N even)
    int nz4 = (N * 9) / 2;
    int Eh = E / 2;

    k_gemm<<<(N + BM - 1) / BM, 256, 0, stream>>>(x, w, att, xwh, a_src, a_dst,
                                                  (float4*)seg, nz4, N);
    k_esum<<<(E * HEADS + 255) / 256, 256, 0, stream>>>(ei, E, a_src, a_dst,
                                                        (__half2*)seg, ealpha);
    k_scatter<<<(Eh + 15) / 16, 256, 0, stream>>>(ei, E, 0, Eh, ealpha, seg, xwh, out_acc2);
    k_scatter<<<(E - Eh + 15) / 16, 256, 0, stream>>>(ei, E, Eh, E, ealpha, seg, xwh, out_acc2);
    k_final<<<(N * 8 + 255) / 256, 256, 0, stream>>>(out_acc2, (const float4*)bias, (float4*)out, N);
}